// Round 1
// baseline (971.622 us; speedup 1.0000x reference)
//
#include <hip/hip_runtime.h>

#define NN 50000
#define EE 800000      // 750000 random + 50000 self-loops
#define IND 512
#define HD 64
#define NB_SCAN 49     // ceil(NN/1024)

__device__ __forceinline__ float lrelu(float x, float s){ return x > 0.f ? x : s*x; }

// ---------------- CSR build (by dst) ----------------
__global__ void k_deg(const int* __restrict__ dst, int* __restrict__ deg){
  int e = blockIdx.x*256 + threadIdx.x;
  if(e < EE) atomicAdd(&deg[dst[e]], 1);
}

__global__ void k_scan1(const int* __restrict__ deg, int* __restrict__ psum){
  __shared__ int sh[256];
  int base = blockIdx.x*1024 + threadIdx.x*4;
  int s = 0;
  #pragma unroll
  for(int j=0;j<4;j++){ int i=base+j; if(i<NN) s += deg[i]; }
  sh[threadIdx.x]=s; __syncthreads();
  for(int st=128; st>0; st>>=1){ if(threadIdx.x<st) sh[threadIdx.x]+=sh[threadIdx.x+st]; __syncthreads(); }
  if(threadIdx.x==0) psum[blockIdx.x]=sh[0];
}

__global__ void k_scan2(int* __restrict__ psum, int nb){
  if(threadIdx.x==0){ int acc=0; for(int i=0;i<nb;i++){ int v=psum[i]; psum[i]=acc; acc+=v; } psum[nb]=acc; }
}

__global__ void k_scan3(const int* __restrict__ deg, const int* __restrict__ psum, int* __restrict__ rowp){
  __shared__ int sh[256];
  int t = threadIdx.x;
  int base = blockIdx.x*1024 + t*4;
  int v[4]; int s=0;
  #pragma unroll
  for(int j=0;j<4;j++){ int i=base+j; v[j] = (i<NN)?deg[i]:0; s+=v[j]; }
  sh[t]=s; __syncthreads();
  for(int st=1; st<256; st<<=1){
    int add = (t>=st)? sh[t-st] : 0;
    __syncthreads();
    sh[t] += add;
    __syncthreads();
  }
  int excl = sh[t]-s + psum[blockIdx.x];
  #pragma unroll
  for(int j=0;j<4;j++){ int i=base+j; if(i<NN){ rowp[i]=excl; excl+=v[j]; } }
  if(blockIdx.x==0 && t==0) rowp[NN] = psum[NB_SCAN];
}

__global__ void k_fill(const int* __restrict__ src, const int* __restrict__ dst,
                       const int* __restrict__ rowp, int* __restrict__ cnt, int* __restrict__ csrc){
  int e = blockIdx.x*256 + threadIdx.x;
  if(e < EE){
    int d = dst[e];
    int p = atomicAdd(&cnt[d], 1);
    csrc[rowp[d] + p] = src[e];
  }
}

// ---------------- shared GEMM tile machinery (64x64 C-tile, 256 thr, 4x4/thr) ----------------
// As stored transposed [k][row] with stride 68 (16B-aligned rows, conflict-light)
__device__ __forceinline__ void load_A_tile(const float* __restrict__ A, int row0, int lda, int kcol0, float* As){
  int t = threadIdx.x;
  int lr = t>>2;             // row 0..63
  int lc = (t&3)*16;         // k base 0/16/32/48
  float4 a[4];
  int row = row0 + lr;
  if(row < NN){
    const float* ap = A + (size_t)row*lda + kcol0 + lc;
    a[0]=*(const float4*)ap; a[1]=*(const float4*)(ap+4); a[2]=*(const float4*)(ap+8); a[3]=*(const float4*)(ap+12);
  } else {
    a[0]=a[1]=a[2]=a[3]=make_float4(0.f,0.f,0.f,0.f);
  }
  const float* av = (const float*)a;
  #pragma unroll
  for(int q=0;q<16;q++) As[(lc+q)*68 + lr] = av[q];
}

__device__ __forceinline__ void load_B_tile(const float* __restrict__ B, int krow0, float* Bs){
  int t = threadIdx.x;
  int bk = t>>2; int lc = (t&3)*16;
  const float* bp = B + (size_t)(krow0+bk)*64 + lc;
  *(float4*)(Bs + bk*64 + lc)      = *(const float4*)bp;
  *(float4*)(Bs + bk*64 + lc + 4)  = *(const float4*)(bp+4);
  *(float4*)(Bs + bk*64 + lc + 8)  = *(const float4*)(bp+8);
  *(float4*)(Bs + bk*64 + lc + 12) = *(const float4*)(bp+12);
}

__device__ __forceinline__ void tile64_compute(const float* __restrict__ As, const float* __restrict__ Bs,
                                               float acc[4][4], int ty, int tx){
  #pragma unroll
  for(int kk=0; kk<64; kk++){
    float4 a = *(const float4*)(As + kk*68 + ty*4);
    float4 b = *(const float4*)(Bs + kk*64 + tx*4);
    acc[0][0]+=a.x*b.x; acc[0][1]+=a.x*b.y; acc[0][2]+=a.x*b.z; acc[0][3]+=a.x*b.w;
    acc[1][0]+=a.y*b.x; acc[1][1]+=a.y*b.y; acc[1][2]+=a.y*b.z; acc[1][3]+=a.y*b.w;
    acc[2][0]+=a.z*b.x; acc[2][1]+=a.z*b.y; acc[2][2]+=a.z*b.z; acc[2][3]+=a.z*b.w;
    acc[3][0]+=a.w*b.x; acc[3][1]+=a.w*b.y; acc[3][2]+=a.w*b.z; acc[3][3]+=a.w*b.w;
  }
}

// proj_feat = ft @ Wp   [NN,512]@[512,64]
__global__ __launch_bounds__(256) void k_gemm_proj(const float* __restrict__ A, const float* __restrict__ B, float* __restrict__ C){
  __shared__ float As[64*68];
  __shared__ float Bs[64*64];
  int row0 = blockIdx.x*64;
  int ty = threadIdx.x>>4, tx = threadIdx.x&15;
  float acc[4][4] = {};
  for(int kt=0; kt<IND; kt+=64){
    __syncthreads();
    load_A_tile(A, row0, IND, kt, As);
    load_B_tile(B, kt, Bs);
    __syncthreads();
    tile64_compute(As, Bs, acc, ty, tx);
  }
  #pragma unroll
  for(int i=0;i<4;i++){
    int row = row0 + ty*4 + i;
    if(row < NN) *(float4*)(C + (size_t)row*64 + tx*4) = make_float4(acc[i][0],acc[i][1],acc[i][2],acc[i][3]);
  }
}

// node matmuls: proj_z = cur@We, pooled = cur@Wg, vals[h] = cur@Wv[h]   (K=64, by selects B)
__global__ __launch_bounds__(256) void k_nodemm(const float* __restrict__ cur, const float* __restrict__ We,
                                                const float* __restrict__ Wg, const float* __restrict__ Wv,
                                                float* __restrict__ projz, float* __restrict__ pooled, float* __restrict__ vals){
  __shared__ float As[64*68];
  __shared__ float Bs[64*64];
  int by = blockIdx.y;
  const float* B; float* C; int ldc;
  if(by==0){ B=We; C=projz; ldc=64; }
  else if(by==1){ B=Wg; C=pooled; ldc=64; }
  else { B = Wv + (size_t)(by-2)*4096; C = vals + (size_t)(by-2)*64; ldc=256; }
  int row0 = blockIdx.x*64;
  int ty = threadIdx.x>>4, tx = threadIdx.x&15;
  float acc[4][4] = {};
  load_A_tile(cur, row0, 64, 0, As);
  load_B_tile(B, 0, Bs);
  __syncthreads();
  tile64_compute(As, Bs, acc, ty, tx);
  #pragma unroll
  for(int i=0;i<4;i++){
    int row = row0 + ty*4 + i;
    if(row < NN) *(float4*)(C + (size_t)row*ldc + tx*4) = make_float4(acc[i][0],acc[i][1],acc[i][2],acc[i][3]);
  }
}

// el/er per node per head (wave per node, butterfly reduce)
__global__ __launch_bounds__(256) void k_eler(const float* __restrict__ projz, const float* __restrict__ al,
                                              const float* __restrict__ ar, float* __restrict__ el, float* __restrict__ er){
  int wid = threadIdx.x>>6, lane = threadIdx.x&63;
  int n = blockIdx.x*4 + wid;
  if(n >= NN) return;
  float z = projz[(size_t)n*64 + lane];
  #pragma unroll
  for(int h=0; h<4; h++){
    float pl = z*al[h*64+lane];
    float pr = z*ar[h*64+lane];
    #pragma unroll
    for(int st=32; st; st>>=1){ pl += __shfl_xor(pl, st, 64); pr += __shfl_xor(pr, st, 64); }
    if(lane==0){ el[(size_t)n*4+h]=pl; er[(size_t)n*4+h]=pr; }
  }
}

// the heavy per-node edge kernel: softmax + weighted agg + GaAN gate + merge, wave per node
template<int LAYER>
__global__ __launch_bounds__(256) void k_edge(const int* __restrict__ rowp, const int* __restrict__ csrc,
    const float* __restrict__ el, const float* __restrict__ er, const float* __restrict__ cur,
    const float* __restrict__ pooled, const float* __restrict__ vals,
    const float* __restrict__ Wg, const float* __restrict__ bg, float* __restrict__ out)
{
  int wid = threadIdx.x>>6, lane = threadIdx.x&63;
  int d = blockIdx.x*4 + wid;
  if(d >= NN) return;
  int e0 = rowp[d], e1 = rowp[d+1];
  float4 erd = *(const float4*)(er + (size_t)d*4);
  // pass 1: per-head max logit (lanes over edges)
  float m0=-1e30f, m1=-1e30f, m2=-1e30f, m3=-1e30f;
  for(int e=e0+lane; e<e1; e+=64){
    int s = csrc[e];
    float4 ev = *(const float4*)(el + (size_t)s*4);
    m0 = fmaxf(m0, lrelu(ev.x+erd.x, 0.2f));
    m1 = fmaxf(m1, lrelu(ev.y+erd.y, 0.2f));
    m2 = fmaxf(m2, lrelu(ev.z+erd.z, 0.2f));
    m3 = fmaxf(m3, lrelu(ev.w+erd.w, 0.2f));
  }
  #pragma unroll
  for(int st=32; st; st>>=1){
    m0=fmaxf(m0,__shfl_xor(m0,st,64)); m1=fmaxf(m1,__shfl_xor(m1,st,64));
    m2=fmaxf(m2,__shfl_xor(m2,st,64)); m3=fmaxf(m3,__shfl_xor(m3,st,64));
  }
  // pass 2: sequential edges, lanes over 64 dims
  float n0=0,n1=0,n2=0,n3=0, d0=0,d1=0,d2=0,d3=0, mn=0, mxp=-1e30f;
  for(int e=e0; e<e1; ++e){
    int s = csrc[e];                                   // wave-uniform
    float4 ev = *(const float4*)(el + (size_t)s*4);    // wave-uniform
    float x0 = __expf(lrelu(ev.x+erd.x,0.2f)-m0);
    float x1 = __expf(lrelu(ev.y+erd.y,0.2f)-m1);
    float x2 = __expf(lrelu(ev.z+erd.z,0.2f)-m2);
    float x3 = __expf(lrelu(ev.w+erd.w,0.2f)-m3);
    d0+=x0; d1+=x1; d2+=x2; d3+=x3;
    const float* vs = vals + (size_t)s*256;
    n0 += x0*vs[lane];
    n1 += x1*vs[64+lane];
    n2 += x2*vs[128+lane];
    n3 += x3*vs[192+lane];
    mn  += cur[(size_t)s*64 + lane];
    mxp  = fmaxf(mxp, pooled[(size_t)s*64 + lane]);
  }
  // GaAN gate
  float cd  = cur[(size_t)d*64 + lane];
  float mnn = mn / (float)(e1-e0);                     // deg == in-degree == row length
  float4 w0 = *(const float4*)(Wg + lane*4);
  float4 w1 = *(const float4*)(Wg + (64+lane)*4);
  float4 w2 = *(const float4*)(Wg + (128+lane)*4);
  float g0 = cd*w0.x + mxp*w1.x + mnn*w2.x;
  float g1 = cd*w0.y + mxp*w1.y + mnn*w2.y;
  float g2 = cd*w0.z + mxp*w1.z + mnn*w2.z;
  float g3 = cd*w0.w + mxp*w1.w + mnn*w2.w;
  #pragma unroll
  for(int st=32; st; st>>=1){
    g0+=__shfl_xor(g0,st,64); g1+=__shfl_xor(g1,st,64);
    g2+=__shfl_xor(g2,st,64); g3+=__shfl_xor(g3,st,64);
  }
  g0 = 1.f/(1.f+__expf(-(g0+bg[0])));
  g1 = 1.f/(1.f+__expf(-(g1+bg[1])));
  g2 = 1.f/(1.f+__expf(-(g2+bg[2])));
  g3 = 1.f/(1.f+__expf(-(g3+bg[3])));
  float a0 = n0/d0*g0, a1 = n1/d1*g1, a2 = n2/d2*g2, a3 = n3/d3*g3;
  if(LAYER==0){
    out[(size_t)d*64 + lane] = lrelu(0.25f*(a0+a1+a2+a3), 0.01f);
  } else {
    out[(size_t)d*256 + lane]       = lrelu(a0, 0.01f);
    out[(size_t)d*256 + 64 + lane]  = lrelu(a1, 0.01f);
    out[(size_t)d*256 + 128 + lane] = lrelu(a2, 0.01f);
    out[(size_t)d*256 + 192 + lane] = lrelu(a3, 0.01f);
  }
}

// out = concat(proj_feat, cur2) @ Wtran + btran   (K=320)
__global__ __launch_bounds__(256) void k_final(const float* __restrict__ pf, const float* __restrict__ cur2,
                                               const float* __restrict__ Wt, const float* __restrict__ bt,
                                               float* __restrict__ C){
  __shared__ float As[64*68];
  __shared__ float Bs[64*64];
  int row0 = blockIdx.x*64;
  int ty = threadIdx.x>>4, tx = threadIdx.x&15;
  float acc[4][4] = {};
  for(int kt=0; kt<320; kt+=64){
    __syncthreads();
    if(kt==0) load_A_tile(pf, row0, 64, 0, As);
    else      load_A_tile(cur2, row0, 256, kt-64, As);
    load_B_tile(Wt, kt, Bs);
    __syncthreads();
    tile64_compute(As, Bs, acc, ty, tx);
  }
  float4 bias = *(const float4*)(bt + tx*4);
  #pragma unroll
  for(int i=0;i<4;i++){
    int row = row0 + ty*4 + i;
    if(row < NN){
      *(float4*)(C + (size_t)row*64 + tx*4) =
        make_float4(acc[i][0]+bias.x, acc[i][1]+bias.y, acc[i][2]+bias.z, acc[i][3]+bias.w);
    }
  }
}

extern "C" void kernel_launch(void* const* d_in, const int* in_sizes, int n_in,
                              void* d_out, int out_size, void* d_ws, size_t ws_size,
                              hipStream_t stream) {
  const float* ft    = (const float*)d_in[0];
  const float* Wp    = (const float*)d_in[1];
  const float* We    = (const float*)d_in[2];
  const float* a_l   = (const float*)d_in[3];
  const float* a_r   = (const float*)d_in[4];
  const float* Wv    = (const float*)d_in[5];
  const float* Wgp   = (const float*)d_in[6];
  const float* Wgate = (const float*)d_in[7];
  const float* bgate = (const float*)d_in[8];
  const float* Wtran = (const float*)d_in[9];
  const float* btran = (const float*)d_in[10];
  const int*   src   = (const int*)d_in[11];
  const int*   dst   = (const int*)d_in[12];
  float* out = (float*)d_out;

  char* p = (char*)d_ws;
  auto alloc = [&](size_t bytes)->char* { char* r = p; p += (bytes + 255) & ~(size_t)255; return r; };
  int* deg  = (int*)alloc((size_t)NN*4);
  int* cnt  = (int*)alloc((size_t)NN*4);
  int* rowp = (int*)alloc((size_t)(NN+1)*4);
  int* psum = (int*)alloc(64*4);
  int* csrc = (int*)alloc((size_t)EE*4);
  float* pf   = (float*)alloc((size_t)NN*64*4);
  float* cur1 = (float*)alloc((size_t)NN*64*4);
  float* cur2 = (float*)alloc((size_t)NN*256*4);
  float* elb  = (float*)alloc((size_t)NN*4*4);
  float* erb  = (float*)alloc((size_t)NN*4*4);
  float* pz   = (float*)alloc((size_t)NN*64*4);
  float* pool = (float*)alloc((size_t)NN*64*4);
  float* vals = (float*)alloc((size_t)NN*256*4);

  hipMemsetAsync(deg, 0, (size_t)NN*4, stream);
  hipMemsetAsync(cnt, 0, (size_t)NN*4, stream);
  k_deg<<<(EE+255)/256, 256, 0, stream>>>(dst, deg);
  k_scan1<<<NB_SCAN, 256, 0, stream>>>(deg, psum);
  k_scan2<<<1, 64, 0, stream>>>(psum, NB_SCAN);
  k_scan3<<<NB_SCAN, 256, 0, stream>>>(deg, psum, rowp);
  k_fill<<<(EE+255)/256, 256, 0, stream>>>(src, dst, rowp, cnt, csrc);

  k_gemm_proj<<<(NN+63)/64, 256, 0, stream>>>(ft, Wp, pf);

  dim3 g6((NN+63)/64, 6);
  // layer 0 (cur = proj_feat)
  k_nodemm<<<g6, 256, 0, stream>>>(pf, We, Wgp, Wv, pz, pool, vals);
  k_eler<<<NN/4, 256, 0, stream>>>(pz, a_l, a_r, elb, erb);
  k_edge<0><<<NN/4, 256, 0, stream>>>(rowp, csrc, elb, erb, pf, pool, vals, Wgate, bgate, cur1);
  // layer 1
  k_nodemm<<<g6, 256, 0, stream>>>(cur1, We, Wgp + 4096, Wv + 16384, pz, pool, vals);
  k_eler<<<NN/4, 256, 0, stream>>>(pz, a_l + 256, a_r + 256, elb, erb);
  k_edge<1><<<NN/4, 256, 0, stream>>>(rowp, csrc, elb, erb, cur1, pool, vals, Wgate + 768, bgate + 4, cur2);

  k_final<<<(NN+63)/64, 256, 0, stream>>>(pf, cur2, Wtran, btran, out);
}